// Round 7
// baseline (334.363 us; speedup 1.0000x reference)
//
#include <hip/hip_runtime.h>

#define DIM 64
#define PRESERVE 0.1f
#define CPAD 16  // one 64B cacheline per counter: kills TCC false-sharing serialization

typedef unsigned short bf16_t;

__device__ __forceinline__ float readlane_f(float v, int l) {
    return __int_as_float(__builtin_amdgcn_readlane(__float_as_int(v), l));
}
__device__ __forceinline__ float bf2f(bf16_t u) {
    return __uint_as_float(((unsigned)u) << 16);
}
__device__ __forceinline__ bf16_t f2bf(float f) {
    unsigned u = __float_as_uint(f);
    unsigned r = (u + 0x7FFFu + ((u >> 16) & 1u)) >> 16;  // RNE
    return (bf16_t)r;
}

// ---------- init (padded counters) ----------
__global__ void k_init(int* cursor, int n) {
    int i = blockIdx.x * blockDim.x + threadIdx.x;
    if (i < n) cursor[(size_t)i * CPAD] = 0;
}

// ---------- histogram + rank: 8 edges/thread, padded counters ----------
__global__ void k_hist8(const int4* __restrict__ col4, int* cursor,
                        int4* __restrict__ rank4, int nvec, int half) {
    int t = blockIdx.x * blockDim.x + threadIdx.x;
    if (t >= half) return;
    int4 c0 = col4[t];
    int v1 = t + half;
    int4 r0;
    r0.x = atomicAdd(&cursor[(size_t)c0.x * CPAD], 1);
    r0.y = atomicAdd(&cursor[(size_t)c0.y * CPAD], 1);
    r0.z = atomicAdd(&cursor[(size_t)c0.z * CPAD], 1);
    r0.w = atomicAdd(&cursor[(size_t)c0.w * CPAD], 1);
    if (v1 < nvec) {
        int4 c1 = col4[v1];
        int4 r1;
        r1.x = atomicAdd(&cursor[(size_t)c1.x * CPAD], 1);
        r1.y = atomicAdd(&cursor[(size_t)c1.y * CPAD], 1);
        r1.z = atomicAdd(&cursor[(size_t)c1.z * CPAD], 1);
        r1.w = atomicAdd(&cursor[(size_t)c1.w * CPAD], 1);
        rank4[v1] = r1;
    }
    rank4[t] = r0;
}

__global__ void k_hist1(const int* __restrict__ col, int* cursor,
                        int* __restrict__ rank, int E) {
    int e = blockIdx.x * blockDim.x + threadIdx.x;
    if (e < E) rank[e] = atomicAdd(&cursor[(size_t)col[e] * CPAD], 1);
}

// ---------- 2-level exclusive scan of counts(=cursor, strided) -> offsets ----------
__global__ __launch_bounds__(256) void k_scan1(const int* __restrict__ counts,
                                               int* __restrict__ offsets,
                                               int* __restrict__ blksum, int n) {
    __shared__ int s[256];
    int t = threadIdx.x;
    int idx = blockIdx.x * 256 + t;
    int v = (idx < n) ? counts[(size_t)idx * CPAD] : 0;
    s[t] = v;
    __syncthreads();
    for (int off = 1; off < 256; off <<= 1) {
        int x = (t >= off) ? s[t - off] : 0;
        __syncthreads();
        s[t] += x;
        __syncthreads();
    }
    if (idx < n) offsets[idx] = s[t];
    if (t == 255) blksum[blockIdx.x] = s[255];
}

__global__ __launch_bounds__(512) void k_scan2(const int* __restrict__ blksum,
                                               int* __restrict__ blkoff, int nblk) {
    __shared__ int s[512];
    int t = threadIdx.x;
    int v = (t < nblk) ? blksum[t] : 0;
    s[t] = v;
    __syncthreads();
    for (int off = 1; off < 512; off <<= 1) {
        int x = (t >= off) ? s[t - off] : 0;
        __syncthreads();
        s[t] += x;
        __syncthreads();
    }
    if (t < nblk) blkoff[t] = s[t] - v;  // exclusive
}

__global__ __launch_bounds__(256) void k_scan3(const int* __restrict__ counts,
                                               int* __restrict__ offsets,
                                               const int* __restrict__ blkoff,
                                               int n, int E) {
    int t = threadIdx.x;
    int idx = blockIdx.x * 256 + t;
    if (idx < n) offsets[idx] = offsets[idx] - counts[(size_t)idx * CPAD] + blkoff[blockIdx.x];
    if (idx == 0) offsets[n] = E;
}

// ---------- bucket-fill CSR: sedge[offsets[col]+rank] = {row, w} ----------
__global__ void k_fill4(const int4* __restrict__ row4, const int4* __restrict__ col4,
                        const float4* __restrict__ w4, const int4* __restrict__ rank4,
                        const int* __restrict__ offsets, int2* __restrict__ sedge,
                        int nthreads) {
    int t = blockIdx.x * blockDim.x + threadIdx.x;
    if (t >= nthreads) return;
    int4 r = row4[t];
    int4 c = col4[t];
    float4 w = w4[t];
    int4 k = rank4[t];
    int2 p;
    p.x = r.x; p.y = __float_as_int(w.x); sedge[offsets[c.x] + k.x] = p;
    p.x = r.y; p.y = __float_as_int(w.y); sedge[offsets[c.y] + k.y] = p;
    p.x = r.z; p.y = __float_as_int(w.z); sedge[offsets[c.z] + k.z] = p;
    p.x = r.w; p.y = __float_as_int(w.w); sedge[offsets[c.w] + k.w] = p;
}

__global__ void k_fill1(const int* __restrict__ row, const int* __restrict__ col,
                        const float* __restrict__ w, const int* __restrict__ rank,
                        const int* __restrict__ offsets, int2* __restrict__ sedge,
                        int E) {
    int e = blockIdx.x * blockDim.x + threadIdx.x;
    if (e >= E) return;
    int2 p;
    p.x = row[e];
    p.y = __float_as_int(w[e]);
    sedge[offsets[col[e]] + rank[e]] = p;
}

// ---------- deg -> dinv from CSR (wave per node, no atomics) ----------
__global__ __launch_bounds__(256) void k_deg_seg(const int2* __restrict__ sedge,
                                                 const int* __restrict__ offsets,
                                                 float* __restrict__ dinv, int n) {
    int tid = threadIdx.x;
    int lane = tid & 63;
    int c = blockIdx.x * 4 + (tid >> 6);
    if (c >= n) return;
    int beg = offsets[c];
    int end = offsets[c + 1];
    float s = 0.0f;
    for (int j = beg + lane; j < end; j += 64) s += __int_as_float(sedge[j].y);
    for (int off = 32; off > 0; off >>= 1) s += __shfl_xor(s, off);
    if (lane == 0) {
        float d = 1.0f + s;  // self-loop weight
        dinv[c] = (d > 0.0f) ? rsqrtf(d) : 0.0f;
    }
}

// ---------- xs = bf16( (x @ W) * dinv[row] ) ----------
__global__ __launch_bounds__(256) void k_mm(
        const float* __restrict__ x, const float* __restrict__ W,
        const float* __restrict__ dinv, bf16_t* __restrict__ xs, int n) {
    int tid = threadIdx.x;
    int lane = tid & 63;
    int waveId = blockIdx.x * 4 + (tid >> 6);
    int nWaves = gridDim.x * 4;

    float Wr[DIM];
#pragma unroll
    for (int k = 0; k < DIM; ++k) Wr[k] = W[k * DIM + lane];

    for (int r0 = waveId * 4; r0 < n; r0 += nWaves * 4) {
        if (r0 + 3 < n) {
            float x0 = x[(size_t)(r0 + 0) * DIM + lane];
            float x1 = x[(size_t)(r0 + 1) * DIM + lane];
            float x2 = x[(size_t)(r0 + 2) * DIM + lane];
            float x3 = x[(size_t)(r0 + 3) * DIM + lane];
            float a0 = 0.f, a1 = 0.f, a2 = 0.f, a3 = 0.f;
#pragma unroll
            for (int k = 0; k < DIM; ++k) {
                float w = Wr[k];
                a0 += readlane_f(x0, k) * w;
                a1 += readlane_f(x1, k) * w;
                a2 += readlane_f(x2, k) * w;
                a3 += readlane_f(x3, k) * w;
            }
            xs[(size_t)(r0 + 0) * DIM + lane] = f2bf(a0 * dinv[r0 + 0]);
            xs[(size_t)(r0 + 1) * DIM + lane] = f2bf(a1 * dinv[r0 + 1]);
            xs[(size_t)(r0 + 2) * DIM + lane] = f2bf(a2 * dinv[r0 + 2]);
            xs[(size_t)(r0 + 3) * DIM + lane] = f2bf(a3 * dinv[r0 + 3]);
        } else {
            for (int r = r0; r < n; ++r) {
                float xv = x[(size_t)r * DIM + lane];
                float a = 0.f;
#pragma unroll
                for (int k = 0; k < DIM; ++k) a += readlane_f(xv, k) * Wr[k];
                xs[(size_t)r * DIM + lane] = f2bf(a * dinv[r]);
            }
        }
    }
}

// ---------- gather (wave per node, lane = dim), bf16 xs rows ----------
__global__ __launch_bounds__(256) void k_gather(
        const bf16_t* __restrict__ xs, const int* __restrict__ offsets,
        const int2* __restrict__ sedge, const float* __restrict__ dinv,
        const float* __restrict__ b, const float* __restrict__ xprev,
        float* __restrict__ out, int n) {
    int tid = threadIdx.x;
    int lane = tid & 63;
    int c = blockIdx.x * 4 + (tid >> 6);
    if (c >= n) return;
    float di = dinv[c];
    float acc = bf2f(xs[(size_t)c * DIM + lane]);
    int beg = offsets[c];
    int end = offsets[c + 1];
    for (int b0 = beg; b0 < end; b0 += 64) {
        int m = end - b0;
        if (m > 64) m = 64;
        int r_l = 0, w_l = 0;
        if (lane < m) {
            int2 p = sedge[b0 + lane];  // coalesced batch load
            r_l = p.x;
            w_l = p.y;
        }
        int j = 0;
        for (; j + 3 < m; j += 4) {
            int r0 = __builtin_amdgcn_readlane(r_l, j);
            int r1 = __builtin_amdgcn_readlane(r_l, j + 1);
            int r2 = __builtin_amdgcn_readlane(r_l, j + 2);
            int r3 = __builtin_amdgcn_readlane(r_l, j + 3);
            float w0 = readlane_f(__int_as_float(w_l), j);
            float w1 = readlane_f(__int_as_float(w_l), j + 1);
            float w2 = readlane_f(__int_as_float(w_l), j + 2);
            float w3 = readlane_f(__int_as_float(w_l), j + 3);
            float a0 = bf2f(xs[(size_t)r0 * DIM + lane]);
            float a1 = bf2f(xs[(size_t)r1 * DIM + lane]);
            float a2 = bf2f(xs[(size_t)r2 * DIM + lane]);
            float a3 = bf2f(xs[(size_t)r3 * DIM + lane]);
            acc += a0 * w0;
            acc += a1 * w1;
            acc += a2 * w2;
            acc += a3 * w3;
        }
        for (; j < m; ++j) {
            int r0 = __builtin_amdgcn_readlane(r_l, j);
            float w0 = readlane_f(__int_as_float(w_l), j);
            acc += bf2f(xs[(size_t)r0 * DIM + lane]) * w0;
        }
    }
    float v = (1.0f - PRESERVE) * (acc * di + b[lane]) + PRESERVE * xprev[(size_t)c * DIM + lane];
    out[(size_t)c * DIM + lane] = v;
}

extern "C" void kernel_launch(void* const* d_in, const int* in_sizes, int n_in,
                              void* d_out, int out_size, void* d_ws, size_t ws_size,
                              hipStream_t stream) {
    const float* x  = (const float*)d_in[0];
    const int*   ei = (const int*)d_in[1];
    const float* ew = (const float*)d_in[2];
    const float* W1 = (const float*)d_in[3];
    const float* b1 = (const float*)d_in[4];
    const float* W2 = (const float*)d_in[5];
    const float* b2 = (const float*)d_in[6];

    const int N = in_sizes[0] / DIM;      // 100000
    const int E = in_sizes[2];            // 1250000
    const int* row = ei;
    const int* col = ei + E;

    // workspace layout (sedge first for 8B alignment)
    int2* sedge   = (int2*)d_ws;                          // E
    float* dinv   = (float*)(sedge + E);                  // N
    float* temp   = dinv + N;                             // N*DIM fp32
    bf16_t* xs    = (bf16_t*)(temp + (size_t)N * DIM);    // N*DIM bf16
    int* rank     = (int*)(xs + (size_t)N * DIM);         // E
    int* cursor   = rank + E;                             // N*CPAD (padded counters)
    int* offsets  = cursor + (size_t)N * CPAD;            // N+1
    int* blksum   = offsets + N + 1;                      // <=640
    int* blkoff   = blksum + 640;                         // <=640

    const int B = 256;
    const int nblkN = (N + B - 1) / B;   // 391 (<=512 for k_scan2)
    const int nblkG = (N + 3) / 4;
    const int nblkMM = 1024;             // grid-stride; 4096 waves

    k_init<<<nblkN, B, 0, stream>>>(cursor, N);

    // histogram + rank
    if ((E & 3) == 0) {
        int nvec = E / 4;
        int half = (nvec + 1) / 2;
        k_hist8<<<(half + B - 1) / B, B, 0, stream>>>((const int4*)col, cursor,
                                                      (int4*)rank, nvec, half);
    } else {
        k_hist1<<<(E + B - 1) / B, B, 0, stream>>>(col, cursor, rank, E);
    }

    // scan counts -> offsets
    k_scan1<<<nblkN, B, 0, stream>>>(cursor, offsets, blksum, N);
    k_scan2<<<1, 512, 0, stream>>>(blksum, blkoff, nblkN);
    k_scan3<<<nblkN, B, 0, stream>>>(cursor, offsets, blkoff, N, E);

    // fill CSR (no atomics)
    if ((E & 3) == 0) {
        int nt = E / 4;
        k_fill4<<<(nt + B - 1) / B, B, 0, stream>>>((const int4*)row, (const int4*)col,
                                                    (const float4*)ew, (const int4*)rank,
                                                    offsets, sedge, nt);
    } else {
        k_fill1<<<(E + B - 1) / B, B, 0, stream>>>(row, col, ew, rank, offsets, sedge, E);
    }

    // dinv from segmented degree sum
    k_deg_seg<<<nblkG, B, 0, stream>>>(sedge, offsets, dinv, N);

    // layer 1
    k_mm<<<nblkMM, B, 0, stream>>>(x, W1, dinv, xs, N);
    k_gather<<<nblkG, B, 0, stream>>>(xs, offsets, sedge, dinv, b1, x, temp, N);

    // layer 2
    k_mm<<<nblkMM, B, 0, stream>>>(temp, W2, dinv, xs, N);
    k_gather<<<nblkG, B, 0, stream>>>(xs, offsets, sedge, dinv, b2, temp, (float*)d_out, N);
}